// Round 7
// baseline (590.477 us; speedup 1.0000x reference)
//
#include <hip/hip_runtime.h>
#include <math.h>

#define NNODES  100000
#define NEDGES  3200000
#define NGRAPHS 1024
#define NBLK    ((NNODES + 255) / 256)     // 391 scan blocks
#define NPART   8                          // one partition per XCD
#define PSTRIDE ((NNODES + NPART - 1) / NPART)
#define CHUNK   8192
#define NCHUNKS ((NEDGES + CHUNK - 1) / CHUNK)   // 391

typedef int iv4 __attribute__((ext_vector_type(4)));   // native vector for nt loads

// ---- bf16x2 pack/unpack (RNE) ----
__device__ __forceinline__ unsigned bf16pair(float a, float b) {
    unsigned ua = __float_as_uint(a), ub = __float_as_uint(b);
    ua += 0x7fffu + ((ua >> 16) & 1u);
    ub += 0x7fffu + ((ub >> 16) & 1u);
    return (ua >> 16) | (ub & 0xffff0000u);
}
__device__ __forceinline__ float bflo(unsigned u) { return __uint_as_float(u << 16); }
__device__ __forceinline__ float bfhi(unsigned u) { return __uint_as_float(u & 0xffff0000u); }

// ---------------- init ----------------

__global__ void zero4_kernel(int4* p, int nvec) {
    int i = blockIdx.x * blockDim.x + threadIdx.x;
    if (i < nvec) p[i] = make_int4(0, 0, 0, 0);
}

// dst-partitioned, XCD-pinned in-degree histogram (nt edge reads)
__global__ void hist_kernel(const int* __restrict__ dst, int* __restrict__ cnt) {
    int p = blockIdx.x & (NPART - 1);
    int c = blockIdx.x / NPART;
    int lo = p * PSTRIDE, hi = lo + PSTRIDE;
    int beg = c * CHUNK;
    int end = beg + CHUNK; if (end > NEDGES) end = NEDGES;
    for (int e = beg + threadIdx.x * 4; e < end; e += 256 * 4) {
        iv4 d4 = __builtin_nontemporal_load((const iv4*)(dst + e));
        if (d4.x >= lo && d4.x < hi) atomicAdd(&cnt[d4.x], 1);
        if (d4.y >= lo && d4.y < hi) atomicAdd(&cnt[d4.y], 1);
        if (d4.z >= lo && d4.z < hi) atomicAdd(&cnt[d4.z], 1);
        if (d4.w >= lo && d4.w < hi) atomicAdd(&cnt[d4.w], 1);
    }
}

// dinv[n]=rsqrt(deg+1); xs[n][f]=x[n][f]*dinv (bf16x2 packed) — thread per float4
__global__ void dinvx_kernel(const int* __restrict__ cnt, const float4* __restrict__ x,
                             float* __restrict__ dinv, unsigned* __restrict__ xs) {
    int t = blockIdx.x * blockDim.x + threadIdx.x;
    if (t >= NNODES * 4) return;
    int n = t >> 2, q = t & 3;
    float di = rsqrtf((float)(cnt[n] + 1));
    if (q == 0) dinv[n] = di;
    float4 v = x[t];
    unsigned p0 = bf16pair(v.x * di, v.y * di);
    unsigned p1 = bf16pair(v.z * di, v.w * di);
    xs[n * 8 + q * 2]     = p0;
    xs[n * 8 + q * 2 + 1] = p1;
}

// ---------------- exclusive scan ----------------

__global__ void scanA_kernel(const int* __restrict__ cnt, int* __restrict__ part,
                             int* __restrict__ bsum) {
    __shared__ int s[256];
    int i = blockIdx.x * 256 + threadIdx.x;
    int v = (i < NNODES) ? cnt[i] : 0;
    s[threadIdx.x] = v;
    __syncthreads();
    for (int off = 1; off < 256; off <<= 1) {
        int t = (threadIdx.x >= off) ? s[threadIdx.x - off] : 0;
        __syncthreads();
        s[threadIdx.x] += t;
        __syncthreads();
    }
    int incl = s[threadIdx.x];
    if (i < NNODES) part[i] = incl - v;
    if (threadIdx.x == 255) bsum[blockIdx.x] = incl;
}

__global__ void scanB_kernel(const int* __restrict__ bsum, int* __restrict__ boff) {
    int lane = threadIdx.x;          // 64 lanes
    int run = 0;
    for (int base = 0; base < NBLK; base += 64) {
        int idx = base + lane;
        int own = (idx < NBLK) ? bsum[idx] : 0;
        int v = own;
        for (int off = 1; off < 64; off <<= 1) {
            int t = __shfl_up(v, off, 64);
            if (lane >= off) v += t;
        }
        if (idx < NBLK) boff[idx] = run + v - own;
        run += __shfl(v, 63, 64);
    }
}

__global__ void scanC_kernel(int* __restrict__ part, const int* __restrict__ boff,
                             int* __restrict__ rowptr, int* __restrict__ cursor) {
    int i = blockIdx.x * 256 + threadIdx.x;
    if (i < NNODES) {
        int v = part[i] + boff[blockIdx.x];
        rowptr[i] = v;
        cursor[i] = v;
    }
}

// ---------------- CSR fill (dst-partitioned, XCD-pinned, nt edge reads) ----------------

__global__ void csr_fill_kernel(const int* __restrict__ src, const int* __restrict__ dst,
                                int* __restrict__ cursor, int* __restrict__ entries) {
    int p = blockIdx.x & (NPART - 1);
    int c = blockIdx.x / NPART;
    int lo = p * PSTRIDE, hi = lo + PSTRIDE;
    int beg = c * CHUNK;
    int end = beg + CHUNK; if (end > NEDGES) end = NEDGES;
    for (int e = beg + threadIdx.x * 4; e < end; e += 256 * 4) {
        iv4 d4 = __builtin_nontemporal_load((const iv4*)(dst + e));
        iv4 s4 = __builtin_nontemporal_load((const iv4*)(src + e));
        if (d4.x >= lo && d4.x < hi) entries[atomicAdd(&cursor[d4.x], 1)] = s4.x;
        if (d4.y >= lo && d4.y < hi) entries[atomicAdd(&cursor[d4.y], 1)] = s4.y;
        if (d4.z >= lo && d4.z < hi) entries[atomicAdd(&cursor[d4.z], 1)] = s4.z;
        if (d4.w >= lo && d4.w < hi) entries[atomicAdd(&cursor[d4.w], 1)] = s4.w;
    }
}

// ---------------- gather 1 (bf16, 8 lanes/node, 2 feats/lane) ----------------

__global__ void gather1_kernel(const int* __restrict__ entries, const int* __restrict__ rowptr,
                               const int* __restrict__ rowend, const float* __restrict__ dinv,
                               const unsigned* __restrict__ xs, unsigned* __restrict__ ax) {
    int t = blockIdx.x * blockDim.x + threadIdx.x;
    int n = t >> 3, lane = t & 7;
    int beg = rowptr[n], end = rowend[n];
    unsigned self = xs[n * 8 + lane];
    float a0 = bflo(self), a1 = bfhi(self);
    for (int base = beg; base < end; base += 8) {
        int m = end - base; if (m > 8) m = 8;
        int s = (lane < m) ? __builtin_nontemporal_load(entries + base + lane) : 0;
        if (m == 8) {
#pragma unroll
            for (int j = 0; j < 8; ++j) {
                unsigned v = xs[__shfl(s, j, 8) * 8 + lane];
                a0 += bflo(v); a1 += bfhi(v);
            }
        } else {
            for (int j = 0; j < m; ++j) {
                unsigned v = xs[__shfl(s, j, 8) * 8 + lane];
                a0 += bflo(v); a1 += bfhi(v);
            }
        }
    }
    float di = dinv[n];
    ax[n * 8 + lane] = bf16pair(a0 * di, a1 * di);
}

// ---------------- fused node MLP: ax -> relu(axW1+b1) -> (h1W2)*dinv -> hm2s ----------------
// 16 nodes/block, 16 lanes/node

__global__ void mlp_kernel(const unsigned* __restrict__ axb, const float* __restrict__ W1,
                           const float* __restrict__ b1, const float* __restrict__ W2,
                           const float* __restrict__ dinv, unsigned* __restrict__ hm2s) {
    __shared__ float w1[16 * 64];
    __shared__ float w2[64 * 32];
    __shared__ float bb1[64];
    __shared__ float axs[16][17];   // +1 pad
    __shared__ float h1s[16][65];   // +1 pad
    int tid = threadIdx.x;
    for (int i = tid; i < 16 * 64; i += 256) w1[i] = W1[i];
    for (int i = tid; i < 64 * 32; i += 256) w2[i] = W2[i];
    if (tid < 64) bb1[tid] = b1[tid];

    int nl = tid >> 4, lane = tid & 15;
    int n = blockIdx.x * 16 + nl;

    if (lane < 8) {
        unsigned v = axb[n * 8 + lane];
        axs[nl][lane * 2]     = bflo(v);
        axs[nl][lane * 2 + 1] = bfhi(v);
    }
    __syncthreads();

    {
        int j0 = lane * 4;
        float h0 = bb1[j0], h1v = bb1[j0 + 1], h2 = bb1[j0 + 2], h3 = bb1[j0 + 3];
#pragma unroll
        for (int k = 0; k < 16; ++k) {
            float a = axs[nl][k];
            const float* wr = w1 + k * 64 + j0;
            h0 += a * wr[0]; h1v += a * wr[1]; h2 += a * wr[2]; h3 += a * wr[3];
        }
        h1s[nl][j0]     = fmaxf(h0, 0.f);
        h1s[nl][j0 + 1] = fmaxf(h1v, 0.f);
        h1s[nl][j0 + 2] = fmaxf(h2, 0.f);
        h1s[nl][j0 + 3] = fmaxf(h3, 0.f);
    }
    __syncthreads();

    {
        int j0 = lane * 2;
        float c0 = 0.f, c1 = 0.f;
#pragma unroll
        for (int k = 0; k < 64; ++k) {
            float hv = h1s[nl][k];
            c0 += hv * w2[k * 32 + j0];
            c1 += hv * w2[k * 32 + j0 + 1];
        }
        float di = dinv[n];
        hm2s[n * 16 + lane] = bf16pair(c0 * di, c1 * di);
    }
}

// ---------------- gather 2 + pool (bf16, 16 lanes/node, 2 feats/lane) ----------------

__global__ void gather2_pool_kernel(const int* __restrict__ entries, const int* __restrict__ rowptr,
                                    const int* __restrict__ rowend, const float* __restrict__ dinv,
                                    const unsigned* __restrict__ hm2s, const float* __restrict__ b2,
                                    const int* __restrict__ batch,
                                    float* __restrict__ psum, float* __restrict__ pcnt) {
    int t = blockIdx.x * blockDim.x + threadIdx.x;
    int n = t >> 4, lane = t & 15;
    int beg = rowptr[n], end = rowend[n];
    unsigned self = hm2s[n * 16 + lane];
    float a0 = bflo(self), a1 = bfhi(self);
    for (int base = beg; base < end; base += 16) {
        int m = end - base; if (m > 16) m = 16;
        int s = (lane < m) ? __builtin_nontemporal_load(entries + base + lane) : 0;
        if (m == 16) {
#pragma unroll
            for (int j = 0; j < 16; ++j) {
                unsigned v = hm2s[__shfl(s, j, 16) * 16 + lane];
                a0 += bflo(v); a1 += bfhi(v);
            }
        } else {
            for (int j = 0; j < m; ++j) {
                unsigned v = hm2s[__shfl(s, j, 16) * 16 + lane];
                a0 += bflo(v); a1 += bfhi(v);
            }
        }
    }
    float di = dinv[n];
    int j0 = lane * 2;
    float v0 = fmaxf(a0 * di + b2[j0], 0.f);
    float v1 = fmaxf(a1 * di + b2[j0 + 1], 0.f);
    int g = batch[n];
    atomicAdd(&psum[g * 32 + j0], v0);
    atomicAdd(&psum[g * 32 + j0 + 1], v1);
    if (lane == 0) atomicAdd(&pcnt[g], 1.0f);
}

// ---------------- head ----------------

__global__ void head_kernel(const float* __restrict__ psum, const float* __restrict__ pcnt,
                            const float* __restrict__ fc1W, const float* __restrict__ fc1b,
                            const float* __restrict__ fc2W, const float* __restrict__ fc2b,
                            float* __restrict__ out) {
    int g = blockIdx.x * blockDim.x + threadIdx.x;
    if (g >= NGRAPHS) return;
    float inv = 1.0f / fmaxf(pcnt[g], 1.0f);
    float gv[32];
#pragma unroll
    for (int k = 0; k < 32; ++k) gv[k] = psum[g * 32 + k] * inv;
    float o = fc2b[0];
#pragma unroll
    for (int j = 0; j < 16; ++j) {
        float h = fc1b[j];
#pragma unroll
        for (int k = 0; k < 32; ++k) h += gv[k] * fc1W[k * 16 + j];
        h = fmaxf(h, 0.f);
        o += h * fc2W[j];
    }
    out[g] = 1.0f / (1.0f + expf(-o));
}

// ---------------- launch ----------------

extern "C" void kernel_launch(void* const* d_in, const int* in_sizes, int n_in,
                              void* d_out, int out_size, void* d_ws, size_t ws_size,
                              hipStream_t stream) {
    const float* x    = (const float*)d_in[0];
    const int*   ei   = (const int*)d_in[1];
    const int*   batch= (const int*)d_in[2];
    const float* W1   = (const float*)d_in[3];
    const float* b1   = (const float*)d_in[4];
    const float* W2   = (const float*)d_in[5];
    const float* b2   = (const float*)d_in[6];
    const float* fc1W = (const float*)d_in[7];
    const float* fc1b = (const float*)d_in[8];
    const float* fc2W = (const float*)d_in[9];
    const float* fc2b = (const float*)d_in[10];
    float* out = (float*)d_out;

    const int* src = ei;
    const int* dst = ei + NEDGES;

    char* wsb = (char*)d_ws;
    int*      cnt    = (int*)wsb;                 // 400000 B  } zeroed span
    float*    psum   = (float*)(wsb + 400000);    // 131072 B  }
    float*    pcnt   = (float*)(wsb + 531072);    // 4096 B    }
    float*    dinv   = (float*)(wsb + 535552);    // 400000 B
    int*      rowptr = (int*)(wsb + 935936);      // 400000 B
    int*      cursor = (int*)(wsb + 1336320);     // 400000 B
    int*      bsum   = (int*)(wsb + 1736704);     // ~2 KB
    int*      boff   = (int*)(wsb + 1738752);     // ~2 KB
    int*      entries= (int*)(wsb + 1740800);     // 12.8 MB
    unsigned* xs     = (unsigned*)(wsb + 14541312);  // 3.2 MB  (bf16x2)
    unsigned* ax     = (unsigned*)(wsb + 17741312);  // 3.2 MB
    unsigned* hm2s   = (unsigned*)(wsb + 20941312);  // 6.4 MB  (ends ~27.4 MB)

    const int B = 256;
    zero4_kernel<<<(33448 + B - 1) / B, B, 0, stream>>>((int4*)cnt, 33448);

    hist_kernel<<<NCHUNKS * NPART, B, 0, stream>>>(dst, cnt);
    dinvx_kernel<<<(NNODES * 4 + B - 1) / B, B, 0, stream>>>(cnt, (const float4*)x, dinv, xs);

    scanA_kernel<<<NBLK, 256, 0, stream>>>(cnt, rowptr, bsum);
    scanB_kernel<<<1, 64, 0, stream>>>(bsum, boff);
    scanC_kernel<<<NBLK, 256, 0, stream>>>(rowptr, boff, rowptr, cursor);

    csr_fill_kernel<<<NCHUNKS * NPART, B, 0, stream>>>(src, dst, cursor, entries);

    gather1_kernel<<<NNODES * 8 / B, B, 0, stream>>>(entries, rowptr, cursor, dinv, xs, ax);
    mlp_kernel<<<NNODES / 16, B, 0, stream>>>(ax, W1, b1, W2, dinv, hm2s);
    gather2_pool_kernel<<<NNODES * 16 / B, B, 0, stream>>>(entries, rowptr, cursor, dinv,
                                                           hm2s, b2, batch, psum, pcnt);
    head_kernel<<<(NGRAPHS + B - 1) / B, B, 0, stream>>>(psum, pcnt, fc1W, fc1b, fc2W, fc2b, out);
}